// Round 7
// baseline (192.452 us; speedup 1.0000x reference)
//
#include <hip/hip_runtime.h>
#include <math.h>

// (B,C,H,W)=(8,256,64,64); NH=NP=4, d=64, Nq=4096, M=B*Nq=32768.
namespace {
constexpr int kC = 256;
constexpr int kNq = 4096;
constexpr int kM = 32768;
}

typedef __attribute__((ext_vector_type(8))) short short8;
typedef __attribute__((ext_vector_type(4))) short short4v;
typedef __attribute__((ext_vector_type(4))) float f32x4;

__device__ inline unsigned short f2bf(float f) {
  union { float f; unsigned u; } v; v.f = f;
  unsigned r = (v.u + 0x7FFFu + ((v.u >> 16) & 1u)) >> 16;  // RNE
  return (unsigned short)r;
}
__device__ inline float bf2f(unsigned short h) {
  union { unsigned u; float f; } v; v.u = ((unsigned)h) << 16; return v.f;
}
__device__ inline float uasf(unsigned u) {
  union { unsigned u; float f; } v; v.u = u; return v.f;
}

// -----------------------------------------------------------------------------
// K0: weight prep (bf16 + transpose) + QP table.
// QP[q][n] = (qpos[q]*scale) @ [W_off|W_att][:,n] + bias[n]  -- the qpos term of
// the offset/attention GEMM is input-independent, so all sin/cos + its GEMM
// contribution are folded here (blocks 0..63), off the hot path.
// -----------------------------------------------------------------------------
__global__ __launch_bounds__(256)
void prep_weights_kernel(const float* __restrict__ Wv, const float* __restrict__ Wo,
                         const float* __restrict__ Woff, const float* __restrict__ Watt,
                         const float* __restrict__ boff, const float* __restrict__ batt,
                         const float* __restrict__ ps,
                         unsigned short* __restrict__ WvT, unsigned short* __restrict__ WoT,
                         unsigned short* __restrict__ WoaT, float* __restrict__ QP) {
  __shared__ unsigned short Aq[64][264];
  const int blk = blockIdx.x;
  const int tid = threadIdx.x;
  const int i = blk * 256 + tid;  // 256 blocks -> i < 65536
  {
    const int n = i >> 8, k = i & 255;
    WvT[i] = f2bf(Wv[k * 256 + n]);
    WoT[i] = f2bf(Wo[k * 256 + n]);
  }
  if (i < 16384) {
    const int j = i >> 8, k = i & 255;
    float v = 0.f;
    if (j < 32) v = Woff[k * 32 + j];
    else if (j < 48) v = Watt[k * 16 + (j - 32)];
    WoaT[i] = f2bf(v);
  }
  if (blk >= 64) return;

  // --- QP tile: 64 queries q = blk*64 .. +63 ---
  const float scale = ps[0];
  const int i2 = (tid < 128) ? tid : (tid - 128);
  const float invf = powf(10000.f, -(float)(2 * i2) * (1.f / 256.f));
  for (int q = 0; q < 64; ++q) {
    const float a = (float)(blk * 64 + q) * invf;
    Aq[q][tid] = f2bf(((tid < 128) ? sinf(a) : cosf(a)) * scale);
  }
  __syncthreads();

  const int lane = tid & 63, w = tid >> 6;
  const int l15 = lane & 15, quad = lane >> 4;
  f32x4 acc[3];
#pragma unroll
  for (int j = 0; j < 3; ++j) acc[j] = (f32x4){0.f, 0.f, 0.f, 0.f};
#pragma unroll
  for (int s = 0; s < 8; ++s) {
    short8 af = *(const short8*)&Aq[w * 16 + l15][s * 32 + quad * 8];
    short8 wf[3];
#pragma unroll
    for (int t = 0; t < 3; ++t)
#pragma unroll
      for (int j = 0; j < 8; ++j) {
        const int k = s * 32 + quad * 8 + j;
        wf[t][j] = (short)f2bf((t < 2) ? Woff[k * 32 + t * 16 + l15]
                                       : Watt[k * 16 + l15]);
      }
#pragma unroll
    for (int j = 0; j < 3; ++j)
      acc[j] = __builtin_amdgcn_mfma_f32_16x16x32_bf16(af, wf[j], acc[j], 0, 0, 0);
  }
#pragma unroll
  for (int j = 0; j < 3; ++j) {
    const int n = j * 16 + l15;
    const float bn = (n < 32) ? boff[n] : batt[n - 32];
#pragma unroll
    for (int r = 0; r < 4; ++r) {
      const int q = blk * 64 + w * 16 + quad * 4 + r;
      QP[q * 48 + n] = acc[j][r] + bn;
    }
  }
}

// -----------------------------------------------------------------------------
// K1: merged LN+transpose+GEMM v3. 1024 blocks, mode = blockIdx&1:
//   mode 0: V  = LN2(x2^T) @ W_val + b_val           (bf16 out)
//   mode 1: RAW= LN1(x1^T) @ [W_off|W_att] + QP[q]   (fp32 out, 48 cols; qpos
//           folded into the precomputed QP table -> no trig here)
// Phase A v3: all 16 float4 x-loads upfront (MLP); mean/var accumulated in
// registers from fp32 (pre-rounding) + shfl_xor wave reduce; scratch is bf16
// with b64 writes/reads. LDS 52.5 KB -> 3 blocks/CU (was 70 KB -> 2).
// Frag layouts [verified r2-r6]: A/B lane = [idx=lane&15][k=quad*8+j];
// C/D: col(l15) = 2nd operand idx, row(quad*4+reg) = 1st operand idx.
// -----------------------------------------------------------------------------
__global__ __launch_bounds__(256)
void fused_ln_gemm_kernel(const float* __restrict__ x1, const float* __restrict__ x2,
                          const float* __restrict__ ln1_g, const float* __restrict__ ln1_b,
                          const float* __restrict__ ln2_g, const float* __restrict__ ln2_b,
                          const unsigned short* __restrict__ WvT,
                          const float* __restrict__ b_val, unsigned short* __restrict__ V,
                          const unsigned short* __restrict__ WoaT,
                          const float* __restrict__ QP, float* __restrict__ RAW) {
  __shared__ unsigned short As[64][264];   // 33792 B (normalized bf16, q x c)
  __shared__ unsigned short sx[256][36];   // 18432 B (bf16 scratch, c x q_w)
  __shared__ float psum[2][32][4];         // 1024 B  (sum/sumsq per q_w, wave)
  __shared__ float smean[64];
  __shared__ float srstd[64];

  const int mode = blockIdx.x & 1;         // 0: val path (x2), 1: offatt (x1)
  const int m0 = (blockIdx.x >> 1) * 64;
  const int b = m0 >> 12;
  const int n0 = m0 & 4095;
  const int tid = threadIdx.x;
  const int lane = tid & 63, w = tid >> 6;
  const float gc = mode ? ln1_g[tid] : ln2_g[tid];
  const float bc = mode ? ln1_b[tid] : ln2_b[tid];
  const float* Xb = (mode ? x1 : x2) + (size_t)b * kC * kNq;

  // ---- all global loads upfront ----
  const int cbase = tid >> 3;              // + it*32
  const int q4 = (tid & 7) * 4;
  float4 v[16];
#pragma unroll
  for (int g = 0; g < 2; ++g)
#pragma unroll
    for (int it = 0; it < 8; ++it)
      v[g * 8 + it] = *(const float4*)&Xb[(size_t)(it * 32 + cbase) * kNq + n0 + g * 32 + q4];

  for (int g = 0; g < 2; ++g) {
    // stats in registers + bf16 scratch (b64 writes, <=2-way banks)
    float s[4] = {0.f, 0.f, 0.f, 0.f}, sq[4] = {0.f, 0.f, 0.f, 0.f};
#pragma unroll
    for (int it = 0; it < 8; ++it) {
      const float4 f4 = v[g * 8 + it];
      const float e[4] = {f4.x, f4.y, f4.z, f4.w};
      short4v pk;
#pragma unroll
      for (int j = 0; j < 4; ++j) {
        s[j] += e[j];
        sq[j] += e[j] * e[j];
        pk[j] = (short)f2bf(e[j]);
      }
      *(short4v*)&sx[it * 32 + cbase][q4] = pk;
    }
    // wave-level butterfly over lane bits 3..5 (c-groups)
#pragma unroll
    for (int d = 8; d <= 32; d <<= 1)
#pragma unroll
      for (int j = 0; j < 4; ++j) {
        s[j] += __shfl_xor(s[j], d);
        sq[j] += __shfl_xor(sq[j], d);
      }
    if (lane < 8) {
#pragma unroll
      for (int j = 0; j < 4; ++j) {
        psum[0][lane * 4 + j][w] = s[j];
        psum[1][lane * 4 + j][w] = sq[j];
      }
    }
    __syncthreads();
    if (tid < 32) {
      float S = 0.f, Q = 0.f;
#pragma unroll
      for (int ww = 0; ww < 4; ++ww) { S += psum[0][tid][ww]; Q += psum[1][tid][ww]; }
      const float m = S * (1.f / 256.f);
      const float var = Q * (1.f / 256.f) - m * m;
      smean[g * 32 + tid] = m;
      srstd[g * 32 + tid] = rsqrtf(var + 1e-5f);
    }
    __syncthreads();
    // normalize: thread = channel c (=tid); b64 scratch reads, b16 As writes
#pragma unroll
    for (int k = 0; k < 8; ++k) {
      const short4v xs = *(const short4v*)&sx[tid][k * 4];
#pragma unroll
      for (int j = 0; j < 4; ++j) {
        const int row = g * 32 + k * 4 + j;
        As[row][tid] = f2bf((bf2f((unsigned short)xs[j]) - smean[row]) * srstd[row] * gc + bc);
      }
    }
    __syncthreads();
  }

  const int l15 = lane & 15, quad = lane >> 4;

  if (mode == 0) {
    // 64x256 GEMM: wave w -> n-range w*64; W frags streamed from L2
    f32x4 acc[4][4];
#pragma unroll
    for (int i = 0; i < 4; ++i)
#pragma unroll
      for (int j = 0; j < 4; ++j) acc[i][j] = (f32x4){0.f, 0.f, 0.f, 0.f};
#pragma unroll
    for (int s = 0; s < 8; ++s) {
      short8 af[4], wf[4];
#pragma unroll
      for (int t = 0; t < 4; ++t) af[t] = *(const short8*)&As[t * 16 + l15][s * 32 + quad * 8];
#pragma unroll
      for (int t = 0; t < 4; ++t)
        wf[t] = *(const short8*)&WvT[(size_t)(w * 64 + t * 16 + l15) * 256 + s * 32 + quad * 8];
#pragma unroll
      for (int i = 0; i < 4; ++i)
#pragma unroll
        for (int j = 0; j < 4; ++j)
          acc[i][j] = __builtin_amdgcn_mfma_f32_16x16x32_bf16(af[i], wf[j], acc[i][j], 0, 0, 0);
    }
#pragma unroll
    for (int i = 0; i < 4; ++i)
#pragma unroll
      for (int j = 0; j < 4; ++j) {
        const int n = w * 64 + j * 16 + l15;
        const float bn = b_val[n];
#pragma unroll
        for (int r = 0; r < 4; ++r) {
          const int m = m0 + i * 16 + quad * 4 + r;
          V[(size_t)m * 256 + n] = f2bf(acc[i][j][r] + bn);
        }
      }
  } else {
    // 64q x 48n: wave w owns q-frag w; j-frags 0..2 cover n=0..47
    f32x4 acc[3];
#pragma unroll
    for (int j = 0; j < 3; ++j) acc[j] = (f32x4){0.f, 0.f, 0.f, 0.f};
#pragma unroll
    for (int s = 0; s < 8; ++s) {
      short8 af = *(const short8*)&As[w * 16 + l15][s * 32 + quad * 8];
      short8 wf[3];
#pragma unroll
      for (int t = 0; t < 3; ++t)
        wf[t] = *(const short8*)&WoaT[(size_t)(t * 16 + l15) * 256 + s * 32 + quad * 8];
#pragma unroll
      for (int j = 0; j < 3; ++j)
        acc[j] = __builtin_amdgcn_mfma_f32_16x16x32_bf16(af, wf[j], acc[j], 0, 0, 0);
    }
#pragma unroll
    for (int j = 0; j < 3; ++j) {
      const int n = j * 16 + l15;
#pragma unroll
      for (int r = 0; r < 4; ++r) {
        const int m = m0 + w * 16 + quad * 4 + r;
        const int q = n0 + w * 16 + quad * 4 + r;
        RAW[(size_t)m * 48 + n] = acc[j][r] + QP[q * 48 + n];
      }
    }
  }
}

// -----------------------------------------------------------------------------
// K2: fused sampling + out-projection + residual (round-6 structure, unchanged).
// Block = 64 queries of one batch; XCD swizzle: batch = blk&7.
// -----------------------------------------------------------------------------
__global__ __launch_bounds__(256)
void sample_out_kernel(const float* __restrict__ RAW, const unsigned short* __restrict__ V,
                       const unsigned short* __restrict__ Wt,  // [256][256] WoT
                       const float* __restrict__ bias, const float* __restrict__ x2,
                       float* __restrict__ OUT) {
  __shared__ unsigned short Bs[64][264];         // AO tile (q x c), 33792 B
  __shared__ __align__(16) char smemA[32768];    // sidx/swgt, then fp32 out tile
  int (*sidx)[4] = (int(*)[4])smemA;             // [1024][4]
  float (*swgt)[4] = (float(*)[4])(smemA + 16384);
  float* ot = (float*)smemA;                     // [128][64] fp32 (epilogue)

  const int blk = blockIdx.x;
  const int b = blk & 7;
  const int tile = blk >> 3;                     // 64 q-tiles per batch
  const int m0 = b * 4096 + tile * 64;
  const int tid = threadIdx.x;

  // ---- S1: corner weights/indices for 64q x 4h x 4p ----
#pragma unroll
  for (int t = 0; t < 4; ++t) {
    const int trip = t * 256 + tid;
    const int q_l = trip >> 4, h = (trip >> 2) & 3, p = trip & 3;
    const int m = m0 + q_l;
    const float* raw = RAW + (size_t)m * 48;
    const float l0 = raw[32 + h * 4 + 0];
    const float l1 = raw[32 + h * 4 + 1];
    const float l2 = raw[32 + h * 4 + 2];
    const float l3 = raw[32 + h * 4 + 3];
    const float mx = fmaxf(fmaxf(l0, l1), fmaxf(l2, l3));
    const float e0 = expf(l0 - mx), e1 = expf(l1 - mx), e2 = expf(l2 - mx), e3 = expf(l3 - mx);
    const float lp = (p == 0) ? e0 : (p == 1) ? e1 : (p == 2) ? e2 : e3;
    const float attp = lp / (e0 + e1 + e2 + e3);

    const float ox = raw[h * 8 + p * 2 + 0];
    const float oy = raw[h * 8 + p * 2 + 1];
    const float px = (float)(m & 63) + ox;       // W=64 cancels the normalizer
    const float py = (float)((m >> 6) & 63) + oy;
    const float fx = floorf(px), fy = floorf(py);
    const float wx = px - fx, wy = py - fy;
    const int x0 = (int)fx, y0 = (int)fy;
#pragma unroll
    for (int c = 0; c < 4; ++c) {
      const int dx = c & 1, dy = c >> 1;
      const int xx = x0 + dx, yy = y0 + dy;
      const bool valid = (xx >= 0) & (xx < 64) & (yy >= 0) & (yy < 64);
      const float wc = (dx ? wx : 1.f - wx) * (dy ? wy : 1.f - wy) * attp;
      swgt[trip][c] = valid ? wc : 0.f;
      const int xc = min(max(xx, 0), 63), yc = min(max(yy, 0), 63);
      sidx[trip][c] = yc * 64 + xc;
    }
  }
  __syncthreads();

  // ---- S2: gather + accumulate -> Bs (bf16) ----
#pragma unroll
  for (int it = 0; it < 8; ++it) {
    const int lin = it * 256 + tid;
    const int q_l = lin >> 5, sub = lin & 31;
    const int h = sub >> 3, c8 = (sub & 7) * 8;
    const int trip0 = q_l * 16 + h * 4;
    const unsigned short* vb = V + (size_t)b * kNq * kC + h * 64 + c8;
    float acc[8] = {};
#pragma unroll
    for (int p = 0; p < 4; ++p) {
      const int4 idx = *(const int4*)&sidx[trip0 + p][0];
      const float4 wv = *(const float4*)&swgt[trip0 + p][0];
      const int ia[4] = {idx.x, idx.y, idx.z, idx.w};
      const float wa[4] = {wv.x, wv.y, wv.z, wv.w};
#pragma unroll
      for (int c = 0; c < 4; ++c) {
        const uint4 u = *(const uint4*)&vb[(size_t)ia[c] * kC];
        const float w = wa[c];
        acc[0] = fmaf(w, uasf(u.x << 16), acc[0]);
        acc[1] = fmaf(w, uasf(u.x & 0xffff0000u), acc[1]);
        acc[2] = fmaf(w, uasf(u.y << 16), acc[2]);
        acc[3] = fmaf(w, uasf(u.y & 0xffff0000u), acc[3]);
        acc[4] = fmaf(w, uasf(u.z << 16), acc[4]);
        acc[5] = fmaf(w, uasf(u.z & 0xffff0000u), acc[5]);
        acc[6] = fmaf(w, uasf(u.w << 16), acc[6]);
        acc[7] = fmaf(w, uasf(u.w & 0xffff0000u), acc[7]);
      }
    }
    short8 outv;
#pragma unroll
    for (int e = 0; e < 8; ++e) outv[e] = (short)f2bf(acc[e]);
    *(short8*)&Bs[q_l][h * 64 + c8] = outv;
  }
  __syncthreads();

  // ---- MFMA: wave w -> c-range w*64 ----
  const int lane = tid & 63, w = tid >> 6;
  const int l15 = lane & 15, quad = lane >> 4;
  f32x4 acc[4][4];
#pragma unroll
  for (int i = 0; i < 4; ++i)
#pragma unroll
    for (int j = 0; j < 4; ++j) acc[i][j] = (f32x4){0.f, 0.f, 0.f, 0.f};
#pragma unroll
  for (int s = 0; s < 8; ++s) {
    short8 wf[4], bf[4];
#pragma unroll
    for (int t = 0; t < 4; ++t)
      wf[t] = *(const short8*)&Wt[(size_t)(w * 64 + t * 16 + l15) * 256 + s * 32 + quad * 8];
#pragma unroll
    for (int t = 0; t < 4; ++t) bf[t] = *(const short8*)&Bs[t * 16 + l15][s * 32 + quad * 8];
#pragma unroll
    for (int i = 0; i < 4; ++i)
#pragma unroll
      for (int j = 0; j < 4; ++j)
        acc[i][j] = __builtin_amdgcn_mfma_f32_16x16x32_bf16(wf[i], bf[j], acc[i][j], 0, 0, 0);
  }

  // ---- Epilogue: LDS-staged transpose -> float4 stores (+bias +x2) ----
  const int whalf = w >> 1;
  const int clbase = (w & 1) * 64;
  for (int ch = 0; ch < 2; ++ch) {
    __syncthreads();
    if (whalf == ch) {
#pragma unroll
      for (int i = 0; i < 4; ++i)
#pragma unroll
        for (int j = 0; j < 4; ++j)
#pragma unroll
          for (int r = 0; r < 4; ++r)
            ot[(clbase + i * 16 + quad * 4 + r) * 64 + j * 16 + l15] = acc[i][j][r];
    }
    __syncthreads();
#pragma unroll
    for (int t = 0; t < 8; ++t) {
      const int lin = t * 256 + tid;
      const int cl = lin >> 4, q4 = (lin & 15) * 4;
      const int c = ch * 128 + cl;
      const size_t rowbase = ((size_t)b * 256 + c) * 4096 + tile * 64;
      const float4 xv = *(const float4*)&x2[rowbase + q4];
      const float bc = bias[c];
      float4 o;
      o.x = ot[cl * 64 + q4 + 0] + bc + xv.x;
      o.y = ot[cl * 64 + q4 + 1] + bc + xv.y;
      o.z = ot[cl * 64 + q4 + 2] + bc + xv.z;
      o.w = ot[cl * 64 + q4 + 3] + bc + xv.w;
      *(float4*)&OUT[rowbase + q4] = o;
    }
  }
}

// -----------------------------------------------------------------------------
extern "C" void kernel_launch(void* const* d_in, const int* in_sizes, int n_in,
                              void* d_out, int out_size, void* d_ws, size_t ws_size,
                              hipStream_t stream) {
  const float* x1 = (const float*)d_in[0];
  const float* x2 = (const float*)d_in[1];
  const float* ln1_g = (const float*)d_in[2];
  const float* ln1_b = (const float*)d_in[3];
  const float* ln2_g = (const float*)d_in[4];
  const float* ln2_b = (const float*)d_in[5];
  const float* pos_scale = (const float*)d_in[6];
  const float* W_off = (const float*)d_in[7];
  const float* b_off = (const float*)d_in[8];
  const float* W_att = (const float*)d_in[9];
  const float* b_att = (const float*)d_in[10];
  const float* W_val = (const float*)d_in[11];
  const float* b_val = (const float*)d_in[12];
  const float* W_out = (const float*)d_in[13];
  const float* b_out = (const float*)d_in[14];
  float* out = (float*)d_out;

  char* ws = (char*)d_ws;
  const size_t plane2 = (size_t)kM * kC * sizeof(unsigned short);  // 16 MiB
  unsigned short* Vb   = (unsigned short*)(ws);
  float* RAW           = (float*)(ws + plane2);
  unsigned short* WvT  = (unsigned short*)(ws + plane2 + (size_t)kM * 48 * 4);
  unsigned short* WoT  = WvT + 65536;
  unsigned short* WoaT = WoT + 65536;
  float* QP            = (float*)(WoaT + 16384);   // [4096][48] fp32

  prep_weights_kernel<<<256, 256, 0, stream>>>(W_val, W_out, W_off, W_att,
                                               b_off, b_att, pos_scale,
                                               WvT, WoT, WoaT, QP);
  fused_ln_gemm_kernel<<<1024, 256, 0, stream>>>(x1, x2, ln1_g, ln1_b, ln2_g, ln2_b,
                                                 WvT, b_val, Vb, WoaT, QP, RAW);
  sample_out_kernel<<<512, 256, 0, stream>>>(RAW, Vb, WoT, b_out, x2, out);
}

// Round 8
// 174.878 us; speedup vs baseline: 1.1005x; 1.1005x over previous
//
#include <hip/hip_runtime.h>
#include <math.h>

// (B,C,H,W)=(8,256,64,64); NH=NP=4, d=64, Nq=4096, M=B*Nq=32768.
namespace {
constexpr int kC = 256;
constexpr int kNq = 4096;
constexpr int kM = 32768;
}

typedef __attribute__((ext_vector_type(8))) short short8;
typedef __attribute__((ext_vector_type(4))) short short4v;
typedef __attribute__((ext_vector_type(4))) float f32x4;

__device__ inline unsigned short f2bf(float f) {
  union { float f; unsigned u; } v; v.f = f;
  unsigned r = (v.u + 0x7FFFu + ((v.u >> 16) & 1u)) >> 16;  // RNE
  return (unsigned short)r;
}
__device__ inline float uasf(unsigned u) {
  union { unsigned u; float f; } v; v.u = u; return v.f;
}

// -----------------------------------------------------------------------------
// K0: weight prep (bf16 + transpose) + QP table.
// QP[q][n] = (qpos[q]*scale) @ [W_off|W_att][:,n] + bias[n].
// v2: QP spread over ALL 256 blocks (16 q each); sin/cos via rotation
// recurrence (one sinf/cosf pair + 16 rotations) instead of 16 libm calls.
// -----------------------------------------------------------------------------
__global__ __launch_bounds__(256)
void prep_weights_kernel(const float* __restrict__ Wv, const float* __restrict__ Wo,
                         const float* __restrict__ Woff, const float* __restrict__ Watt,
                         const float* __restrict__ boff, const float* __restrict__ batt,
                         const float* __restrict__ ps,
                         unsigned short* __restrict__ WvT, unsigned short* __restrict__ WoT,
                         unsigned short* __restrict__ WoaT, float* __restrict__ QP) {
  __shared__ unsigned short Aq[16][264];
  const int blk = blockIdx.x;
  const int tid = threadIdx.x;
  const int i = blk * 256 + tid;  // 256 blocks -> i < 65536
  {
    const int n = i >> 8, k = i & 255;
    WvT[i] = f2bf(Wv[k * 256 + n]);
    WoT[i] = f2bf(Wo[k * 256 + n]);
  }
  if (i < 16384) {
    const int j = i >> 8, k = i & 255;
    float v = 0.f;
    if (j < 32) v = Woff[k * 32 + j];
    else if (j < 48) v = Watt[k * 16 + (j - 32)];
    WoaT[i] = f2bf(v);
  }

  // --- QP tile: 16 queries q = blk*16 .. +15, thread = channel ---
  const float scale = ps[0];
  const int i2 = (tid < 128) ? tid : (tid - 128);
  const float invf = powf(10000.f, -(float)(2 * i2) * (1.f / 256.f));
  const int q0 = blk * 16;
  const float a0 = (float)q0 * invf;
  float sv = sinf(a0), cv = cosf(a0);
  const float sd = sinf(invf), cd = cosf(invf);
#pragma unroll
  for (int q = 0; q < 16; ++q) {
    Aq[q][tid] = f2bf(((tid < 128) ? sv : cv) * scale);
    const float ns = sv * cd + cv * sd;
    const float nc = cv * cd - sv * sd;
    sv = ns; cv = nc;
  }
  __syncthreads();

  const int lane = tid & 63, w = tid >> 6;
  const int l15 = lane & 15, quad = lane >> 4;
  if (w < 3) {  // n-frag w covers n = w*16 .. +15 (48 live columns)
    f32x4 acc = (f32x4){0.f, 0.f, 0.f, 0.f};
#pragma unroll
    for (int s = 0; s < 8; ++s) {
      const short8 af = *(const short8*)&Aq[l15][s * 32 + quad * 8];
      short8 wf;
#pragma unroll
      for (int j = 0; j < 8; ++j) {
        const int k = s * 32 + quad * 8 + j;
        wf[j] = (short)f2bf((w < 2) ? Woff[k * 32 + w * 16 + l15]
                                    : Watt[k * 16 + l15]);
      }
      acc = __builtin_amdgcn_mfma_f32_16x16x32_bf16(af, wf, acc, 0, 0, 0);
    }
    const int n = w * 16 + l15;
    const float bn = (n < 32) ? boff[n] : batt[n - 32];
#pragma unroll
    for (int r = 0; r < 4; ++r) {
      const int q = q0 + quad * 4 + r;
      QP[q * 48 + n] = acc[r] + bn;
    }
  }
}

// -----------------------------------------------------------------------------
// K1: merged LN+transpose+GEMM v4. 1024 blocks, mode = blockIdx&1:
//   mode 0: V  = LN2(x2^T) @ W_val + b_val           (bf16 out)
//   mode 1: RAW= LN1(x1^T) @ [W_off|W_att] + QP[q]   (fp32 out, 48 cols)
// Phase A v4 (NO LDS scratch): thread owns 8 consecutive channels x 4 queries
// in registers (c=(tid>>3)*8+it, q=(tid&7)*4+j). Stats: register accumulate +
// shfl_xor butterfly (lane bits 3-5) + psum cross-wave exchange. Normalize
// from registers, write As[q][c] directly as b64 short4 (4/bank = optimal).
// LDS 35.5 KB -> 4 blocks/CU (16 waves); 3 barriers total.
// Frag layouts [verified r2-r7]: A/B lane = [idx=lane&15][k=quad*8+j];
// C/D: col(l15) = 2nd operand idx, row(quad*4+reg) = 1st operand idx.
// -----------------------------------------------------------------------------
__global__ __launch_bounds__(256, 4)
void fused_ln_gemm_kernel(const float* __restrict__ x1, const float* __restrict__ x2,
                          const float* __restrict__ ln1_g, const float* __restrict__ ln1_b,
                          const float* __restrict__ ln2_g, const float* __restrict__ ln2_b,
                          const unsigned short* __restrict__ WvT,
                          const float* __restrict__ b_val, unsigned short* __restrict__ V,
                          const unsigned short* __restrict__ WoaT,
                          const float* __restrict__ QP, float* __restrict__ RAW) {
  __shared__ unsigned short As[64][264];   // 33792 B (normalized bf16, q x c)
  __shared__ float psum[2][32][4];         // 1024 B
  __shared__ float psq[2][32][4];          // 1024 B
  __shared__ float smean[64];
  __shared__ float srstd[64];

  const int mode = blockIdx.x & 1;         // 0: val path (x2), 1: offatt (x1)
  const int m0 = (blockIdx.x >> 1) * 64;
  const int b = m0 >> 12;
  const int n0 = m0 & 4095;
  const int tid = threadIdx.x;
  const int lane = tid & 63, w = tid >> 6;
  const int l7 = tid & 7;                  // q-slice within group
  const int q4 = l7 * 4;
  const int cb8 = (tid >> 3) * 8;          // this thread's 8 consecutive channels
  const float* Xb = (mode ? x1 : x2) + (size_t)b * kC * kNq;
  const float* gptr = mode ? ln1_g : ln2_g;
  const float* bptr = mode ? ln1_b : ln2_b;

  float4 gm[2], bv[2];
  gm[0] = *(const float4*)&gptr[cb8];
  gm[1] = *(const float4*)&gptr[cb8 + 4];
  bv[0] = *(const float4*)&bptr[cb8];
  bv[1] = *(const float4*)&bptr[cb8 + 4];

  // ---- all 16 global float4 loads upfront ----
  float4 v[16];
#pragma unroll
  for (int g = 0; g < 2; ++g)
#pragma unroll
    for (int it = 0; it < 8; ++it)
      v[g * 8 + it] = *(const float4*)&Xb[(size_t)(cb8 + it) * kNq + n0 + g * 32 + q4];

  // ---- stats in registers ----
  float s[2][4] = {}, sq[2][4] = {};
#pragma unroll
  for (int g = 0; g < 2; ++g)
#pragma unroll
    for (int it = 0; it < 8; ++it) {
      const float* e = (const float*)&v[g * 8 + it];
#pragma unroll
      for (int j = 0; j < 4; ++j) {
        s[g][j] += e[j];
        sq[g][j] += e[j] * e[j];
      }
    }
  // butterfly over lane bits 3..5 (sums the 8 channel-groups in this wave)
#pragma unroll
  for (int d = 8; d <= 32; d <<= 1)
#pragma unroll
    for (int g = 0; g < 2; ++g)
#pragma unroll
      for (int j = 0; j < 4; ++j) {
        s[g][j] += __shfl_xor(s[g][j], d);
        sq[g][j] += __shfl_xor(sq[g][j], d);
      }
  if (lane < 8) {
#pragma unroll
    for (int g = 0; g < 2; ++g)
#pragma unroll
      for (int j = 0; j < 4; ++j) {
        psum[g][q4 + j][w] = s[g][j];
        psq[g][q4 + j][w] = sq[g][j];
      }
  }
  __syncthreads();
  if (tid < 64) {
    const int g = tid >> 5, qq = tid & 31;
    float S = 0.f, Q = 0.f;
#pragma unroll
    for (int ww = 0; ww < 4; ++ww) { S += psum[g][qq][ww]; Q += psq[g][qq][ww]; }
    const float m = S * (1.f / 256.f);
    const float var = Q * (1.f / 256.f) - m * m;
    smean[tid] = m;
    srstd[tid] = rsqrtf(var + 1e-5f);
  }
  __syncthreads();

  // ---- normalize from registers, b64 writes to As[q][c] ----
#pragma unroll
  for (int g = 0; g < 2; ++g) {
    const float4 mn = *(const float4*)&smean[g * 32 + q4];
    const float4 rs = *(const float4*)&srstd[g * 32 + q4];
    const float* mnp = (const float*)&mn;
    const float* rsp = (const float*)&rs;
#pragma unroll
    for (int j = 0; j < 4; ++j) {
      const int row = g * 32 + q4 + j;
      short4v pk0, pk1;
#pragma unroll
      for (int it = 0; it < 4; ++it) {
        const float e0 = ((const float*)&v[g * 8 + it])[j];
        const float e1 = ((const float*)&v[g * 8 + 4 + it])[j];
        pk0[it] = (short)f2bf((e0 - mnp[j]) * rsp[j] * ((const float*)gm)[it] + ((const float*)bv)[it]);
        pk1[it] = (short)f2bf((e1 - mnp[j]) * rsp[j] * ((const float*)gm)[4 + it] + ((const float*)bv)[4 + it]);
      }
      *(short4v*)&As[row][cb8] = pk0;
      *(short4v*)&As[row][cb8 + 4] = pk1;
    }
  }
  __syncthreads();

  const int l15 = lane & 15, quad = lane >> 4;

  if (mode == 0) {
    // 64x256 GEMM: wave w -> n-range w*64; W frags streamed from L2
    f32x4 acc[4][4];
#pragma unroll
    for (int i = 0; i < 4; ++i)
#pragma unroll
      for (int j = 0; j < 4; ++j) acc[i][j] = (f32x4){0.f, 0.f, 0.f, 0.f};
#pragma unroll
    for (int s2 = 0; s2 < 8; ++s2) {
      short8 af[4], wf[4];
#pragma unroll
      for (int t = 0; t < 4; ++t) af[t] = *(const short8*)&As[t * 16 + l15][s2 * 32 + quad * 8];
#pragma unroll
      for (int t = 0; t < 4; ++t)
        wf[t] = *(const short8*)&WvT[(size_t)(w * 64 + t * 16 + l15) * 256 + s2 * 32 + quad * 8];
#pragma unroll
      for (int i = 0; i < 4; ++i)
#pragma unroll
        for (int j = 0; j < 4; ++j)
          acc[i][j] = __builtin_amdgcn_mfma_f32_16x16x32_bf16(af[i], wf[j], acc[i][j], 0, 0, 0);
    }
#pragma unroll
    for (int i = 0; i < 4; ++i)
#pragma unroll
      for (int j = 0; j < 4; ++j) {
        const int n = w * 64 + j * 16 + l15;
        const float bn = b_val[n];
#pragma unroll
        for (int r = 0; r < 4; ++r) {
          const int m = m0 + i * 16 + quad * 4 + r;
          V[(size_t)m * 256 + n] = f2bf(acc[i][j][r] + bn);
        }
      }
  } else {
    // 64q x 48n: wave w owns q-frag w; j-frags 0..2 cover n=0..47
    f32x4 acc[3];
#pragma unroll
    for (int j = 0; j < 3; ++j) acc[j] = (f32x4){0.f, 0.f, 0.f, 0.f};
#pragma unroll
    for (int s2 = 0; s2 < 8; ++s2) {
      short8 af = *(const short8*)&As[w * 16 + l15][s2 * 32 + quad * 8];
      short8 wf[3];
#pragma unroll
      for (int t = 0; t < 3; ++t)
        wf[t] = *(const short8*)&WoaT[(size_t)(t * 16 + l15) * 256 + s2 * 32 + quad * 8];
#pragma unroll
      for (int j = 0; j < 3; ++j)
        acc[j] = __builtin_amdgcn_mfma_f32_16x16x32_bf16(af, wf[j], acc[j], 0, 0, 0);
    }
#pragma unroll
    for (int j = 0; j < 3; ++j) {
      const int n = j * 16 + l15;
#pragma unroll
      for (int r = 0; r < 4; ++r) {
        const int m = m0 + w * 16 + quad * 4 + r;
        const int q = n0 + w * 16 + quad * 4 + r;
        RAW[(size_t)m * 48 + n] = acc[j][r] + QP[q * 48 + n];
      }
    }
  }
}

// -----------------------------------------------------------------------------
// K2: fused sampling + out-projection + residual (unchanged from r6/r7).
// Block = 64 queries of one batch; XCD swizzle: batch = blk&7.
// -----------------------------------------------------------------------------
__global__ __launch_bounds__(256)
void sample_out_kernel(const float* __restrict__ RAW, const unsigned short* __restrict__ V,
                       const unsigned short* __restrict__ Wt,  // [256][256] WoT
                       const float* __restrict__ bias, const float* __restrict__ x2,
                       float* __restrict__ OUT) {
  __shared__ unsigned short Bs[64][264];         // AO tile (q x c), 33792 B
  __shared__ __align__(16) char smemA[32768];    // sidx/swgt, then fp32 out tile
  int (*sidx)[4] = (int(*)[4])smemA;             // [1024][4]
  float (*swgt)[4] = (float(*)[4])(smemA + 16384);
  float* ot = (float*)smemA;                     // [128][64] fp32 (epilogue)

  const int blk = blockIdx.x;
  const int b = blk & 7;
  const int tile = blk >> 3;                     // 64 q-tiles per batch
  const int m0 = b * 4096 + tile * 64;
  const int tid = threadIdx.x;

  // ---- S1: corner weights/indices for 64q x 4h x 4p ----
#pragma unroll
  for (int t = 0; t < 4; ++t) {
    const int trip = t * 256 + tid;
    const int q_l = trip >> 4, h = (trip >> 2) & 3, p = trip & 3;
    const int m = m0 + q_l;
    const float* raw = RAW + (size_t)m * 48;
    const float l0 = raw[32 + h * 4 + 0];
    const float l1 = raw[32 + h * 4 + 1];
    const float l2 = raw[32 + h * 4 + 2];
    const float l3 = raw[32 + h * 4 + 3];
    const float mx = fmaxf(fmaxf(l0, l1), fmaxf(l2, l3));
    const float e0 = expf(l0 - mx), e1 = expf(l1 - mx), e2 = expf(l2 - mx), e3 = expf(l3 - mx);
    const float lp = (p == 0) ? e0 : (p == 1) ? e1 : (p == 2) ? e2 : e3;
    const float attp = lp / (e0 + e1 + e2 + e3);

    const float ox = raw[h * 8 + p * 2 + 0];
    const float oy = raw[h * 8 + p * 2 + 1];
    const float px = (float)(m & 63) + ox;       // W=64 cancels the normalizer
    const float py = (float)((m >> 6) & 63) + oy;
    const float fx = floorf(px), fy = floorf(py);
    const float wx = px - fx, wy = py - fy;
    const int x0 = (int)fx, y0 = (int)fy;
#pragma unroll
    for (int c = 0; c < 4; ++c) {
      const int dx = c & 1, dy = c >> 1;
      const int xx = x0 + dx, yy = y0 + dy;
      const bool valid = (xx >= 0) & (xx < 64) & (yy >= 0) & (yy < 64);
      const float wc = (dx ? wx : 1.f - wx) * (dy ? wy : 1.f - wy) * attp;
      swgt[trip][c] = valid ? wc : 0.f;
      const int xc = min(max(xx, 0), 63), yc = min(max(yy, 0), 63);
      sidx[trip][c] = yc * 64 + xc;
    }
  }
  __syncthreads();

  // ---- S2: gather + accumulate -> Bs (bf16) ----
#pragma unroll
  for (int it = 0; it < 8; ++it) {
    const int lin = it * 256 + tid;
    const int q_l = lin >> 5, sub = lin & 31;
    const int h = sub >> 3, c8 = (sub & 7) * 8;
    const int trip0 = q_l * 16 + h * 4;
    const unsigned short* vb = V + (size_t)b * kNq * kC + h * 64 + c8;
    float acc[8] = {};
#pragma unroll
    for (int p = 0; p < 4; ++p) {
      const int4 idx = *(const int4*)&sidx[trip0 + p][0];
      const float4 wv = *(const float4*)&swgt[trip0 + p][0];
      const int ia[4] = {idx.x, idx.y, idx.z, idx.w};
      const float wa[4] = {wv.x, wv.y, wv.z, wv.w};
#pragma unroll
      for (int c = 0; c < 4; ++c) {
        const uint4 u = *(const uint4*)&vb[(size_t)ia[c] * kC];
        const float w = wa[c];
        acc[0] = fmaf(w, uasf(u.x << 16), acc[0]);
        acc[1] = fmaf(w, uasf(u.x & 0xffff0000u), acc[1]);
        acc[2] = fmaf(w, uasf(u.y << 16), acc[2]);
        acc[3] = fmaf(w, uasf(u.y & 0xffff0000u), acc[3]);
        acc[4] = fmaf(w, uasf(u.z << 16), acc[4]);
        acc[5] = fmaf(w, uasf(u.z & 0xffff0000u), acc[5]);
        acc[6] = fmaf(w, uasf(u.w << 16), acc[6]);
        acc[7] = fmaf(w, uasf(u.w & 0xffff0000u), acc[7]);
      }
    }
    short8 outv;
#pragma unroll
    for (int e = 0; e < 8; ++e) outv[e] = (short)f2bf(acc[e]);
    *(short8*)&Bs[q_l][h * 64 + c8] = outv;
  }
  __syncthreads();

  // ---- MFMA: wave w -> c-range w*64 ----
  const int lane = tid & 63, w = tid >> 6;
  const int l15 = lane & 15, quad = lane >> 4;
  f32x4 acc[4][4];
#pragma unroll
  for (int i = 0; i < 4; ++i)
#pragma unroll
    for (int j = 0; j < 4; ++j) acc[i][j] = (f32x4){0.f, 0.f, 0.f, 0.f};
#pragma unroll
  for (int s = 0; s < 8; ++s) {
    short8 wf[4], bf[4];
#pragma unroll
    for (int t = 0; t < 4; ++t)
      wf[t] = *(const short8*)&Wt[(size_t)(w * 64 + t * 16 + l15) * 256 + s * 32 + quad * 8];
#pragma unroll
    for (int t = 0; t < 4; ++t) bf[t] = *(const short8*)&Bs[t * 16 + l15][s * 32 + quad * 8];
#pragma unroll
    for (int i = 0; i < 4; ++i)
#pragma unroll
      for (int j = 0; j < 4; ++j)
        acc[i][j] = __builtin_amdgcn_mfma_f32_16x16x32_bf16(wf[i], bf[j], acc[i][j], 0, 0, 0);
  }

  // ---- Epilogue: LDS-staged transpose -> float4 stores (+bias +x2) ----
  const int whalf = w >> 1;
  const int clbase = (w & 1) * 64;
  for (int ch = 0; ch < 2; ++ch) {
    __syncthreads();
    if (whalf == ch) {
#pragma unroll
      for (int i = 0; i < 4; ++i)
#pragma unroll
        for (int j = 0; j < 4; ++j)
#pragma unroll
          for (int r = 0; r < 4; ++r)
            ot[(clbase + i * 16 + quad * 4 + r) * 64 + j * 16 + l15] = acc[i][j][r];
    }
    __syncthreads();
#pragma unroll
    for (int t = 0; t < 8; ++t) {
      const int lin = t * 256 + tid;
      const int cl = lin >> 4, q4 = (lin & 15) * 4;
      const int c = ch * 128 + cl;
      const size_t rowbase = ((size_t)b * 256 + c) * 4096 + tile * 64;
      const float4 xv = *(const float4*)&x2[rowbase + q4];
      const float bc = bias[c];
      float4 o;
      o.x = ot[cl * 64 + q4 + 0] + bc + xv.x;
      o.y = ot[cl * 64 + q4 + 1] + bc + xv.y;
      o.z = ot[cl * 64 + q4 + 2] + bc + xv.z;
      o.w = ot[cl * 64 + q4 + 3] + bc + xv.w;
      *(float4*)&OUT[rowbase + q4] = o;
    }
  }
}

// -----------------------------------------------------------------------------
extern "C" void kernel_launch(void* const* d_in, const int* in_sizes, int n_in,
                              void* d_out, int out_size, void* d_ws, size_t ws_size,
                              hipStream_t stream) {
  const float* x1 = (const float*)d_in[0];
  const float* x2 = (const float*)d_in[1];
  const float* ln1_g = (const float*)d_in[2];
  const float* ln1_b = (const float*)d_in[3];
  const float* ln2_g = (const float*)d_in[4];
  const float* ln2_b = (const float*)d_in[5];
  const float* pos_scale = (const float*)d_in[6];
  const float* W_off = (const float*)d_in[7];
  const float* b_off = (const float*)d_in[8];
  const float* W_att = (const float*)d_in[9];
  const float* b_att = (const float*)d_in[10];
  const float* W_val = (const float*)d_in[11];
  const float* b_val = (const float*)d_in[12];
  const float* W_out = (const float*)d_in[13];
  const float* b_out = (const float*)d_in[14];
  float* out = (float*)d_out;

  char* ws = (char*)d_ws;
  const size_t plane2 = (size_t)kM * kC * sizeof(unsigned short);  // 16 MiB
  unsigned short* Vb   = (unsigned short*)(ws);
  float* RAW           = (float*)(ws + plane2);
  unsigned short* WvT  = (unsigned short*)(ws + plane2 + (size_t)kM * 48 * 4);
  unsigned short* WoT  = WvT + 65536;
  unsigned short* WoaT = WoT + 65536;
  float* QP            = (float*)(WoaT + 16384);   // [4096][48] fp32

  prep_weights_kernel<<<256, 256, 0, stream>>>(W_val, W_out, W_off, W_att,
                                               b_off, b_att, pos_scale,
                                               WvT, WoT, WoaT, QP);
  fused_ln_gemm_kernel<<<1024, 256, 0, stream>>>(x1, x2, ln1_g, ln1_b, ln2_g, ln2_b,
                                                 WvT, b_val, Vb, WoaT, QP, RAW);
  sample_out_kernel<<<512, 256, 0, stream>>>(RAW, Vb, WoT, b_out, x2, out);
}